// Round 11
// baseline (63.356 us; speedup 1.0000x reference)
//
#include <hip/hip_runtime.h>
#include <stdint.h>

#define MDIM 4096
#define NDIM 1024
#define KDIM 512
#define TSTEPS 50
#define NCH 24            // 3 split-segments x 8 chunks of BK=64

typedef _Float16 half8 __attribute__((ext_vector_type(8)));
typedef float    f32x4 __attribute__((ext_vector_type(4)));

typedef const __attribute__((address_space(1))) void cgv_t;
typedef __attribute__((address_space(3))) void lv_t;

__device__ __forceinline__ void gload16(const void* g, void* s) {
    __builtin_amdgcn_global_load_lds((cgv_t*)g, (lv_t*)s, 16, 0, 0);
}

// Fused pre-kernel: split fp32 -> (f16, f16 residual*2048) for A and W^T,
// row-image layout with the chunk-local XOR swizzle BAKED IN: half8 group k8
// of row r lands at byte (k8>>3)*128 + (((k8&7)*16) ^ ((r&7)<<4)) of the 1KB
// row image. GEMM stages rows linearly via global_load_lds (dest linear =
// swizzled source) and applies the same XOR on ds_read (both-sides rule).
__global__ __launch_bounds__(256) void split_kernel(
    const float* __restrict__ A, const float* __restrict__ W,
    _Float16* __restrict__ A1, _Float16* __restrict__ A2,
    _Float16* __restrict__ B1, _Float16* __restrict__ B2,
    float* __restrict__ tot)
{
    const int blk = blockIdx.x;
    if (blk < 1024) {               // A path: 262144 items = 4096 rows x 64 k8
        int idx = blk * 256 + threadIdx.x;
        if (idx < MDIM) tot[idx] = 0.0f;    // fused tot-zeroing
        int r = idx >> 6, k8 = idx & 63;
        float4 v0 = *(const float4*)(A + (size_t)r * KDIM + k8 * 8);
        float4 v1 = *(const float4*)(A + (size_t)r * KDIM + k8 * 8 + 4);
        float v[8] = {v0.x, v0.y, v0.z, v0.w, v1.x, v1.y, v1.z, v1.w};
        half8 h1, h2;
        #pragma unroll
        for (int e = 0; e < 8; ++e) {
            h1[e] = (_Float16)v[e];
            h2[e] = (_Float16)((v[e] - (float)h1[e]) * 2048.0f);
        }
        int off = r * 1024 + (k8 >> 3) * 128 + (((k8 & 7) * 16) ^ ((r & 7) << 4));
        *(half8*)((char*)A1 + off) = h1;
        *(half8*)((char*)A2 + off) = h2;
    } else {                        // W path: 65536 items = 1024 n x 64 k8
        int idx = (blk - 1024) * 256 + threadIdx.x;
        int n = idx >> 6, k8 = idx & 63;
        float v[8];
        #pragma unroll
        for (int e = 0; e < 8; ++e) v[e] = W[(size_t)(k8 * 8 + e) * NDIM + n];
        half8 h1, h2;
        #pragma unroll
        for (int e = 0; e < 8; ++e) {
            h1[e] = (_Float16)v[e];
            h2[e] = (_Float16)((v[e] - (float)h1[e]) * 2048.0f);
        }
        int off = n * 1024 + (k8 >> 3) * 128 + (((k8 & 7) * 16) ^ ((n & 7) << 4));
        *(half8*)((char*)B1 + off) = h1;
        *(half8*)((char*)B2 + off) = h2;
    }
}

// Split-2 f16 MFMA GEMM + fused LIF (R10 numerics, bit-identical):
// ch 0-7: a2s*b1 ; ch 8-15: a1*b2s ; [acc *= 2^-11] ; ch 16-23: a1*b1.
// 64x64 tile, 256 thr (4 waves, each 32x32 = 2x2 frags of 16x16x32).
// R11: 3-buffer LDS -> ONE barrier per chunk, stage issued right after the
// barrier (overlaps compute, 2 chunks of DMA always in flight, vmcnt(4)
// counted wait), T5 setprio around the compute phase. 3 blocks/CU (48KB LDS).
__global__ __launch_bounds__(256, 3) void snn_mfma_kernel(
    const _Float16* __restrict__ A1, const _Float16* __restrict__ A2,
    const _Float16* __restrict__ B1, const _Float16* __restrict__ B2,
    const float* __restrict__ bias, float* __restrict__ agg, float* __restrict__ tot)
{
    __shared__ __align__(16) unsigned char lds[3][16384];  // A 8KB | B 8KB per buf

    const int t  = threadIdx.x;
    const int l  = t & 63;
    const int w  = t >> 6;
    const int li = l & 15;
    const int lg = l >> 4;
    const int qr = (w >> 1) * 32;   // wave quadrant
    const int qc = (w & 1) * 32;

    // XCD swizzle (bijective, 1024 = 8 x 128)
    const int swz = (blockIdx.x & 7) * 128 + (blockIdx.x >> 3);
    const int m0 = (swz >> 4) * 64;
    const int n0 = (swz & 15) * 64;

    // staging: per chunk 2 A-gload16 + 2 B-gload16 per thread
    int aoff[2], boff[2], dstA[2], dstB[2];
    #pragma unroll
    for (int i_ = 0; i_ < 2; ++i_) {
        int rr  = i_ * 32 + w * 8 + (l >> 3);
        aoff[i_] = (m0 + rr) * 1024 + (l & 7) * 16;
        boff[i_] = (n0 + rr) * 1024 + (l & 7) * 16;
        dstA[i_] = (i_ * 32 + w * 8) * 128;
        dstB[i_] = 8192 + (i_ * 32 + w * 8) * 128;
    }

#define STAGE(buf, ch) do {                                                   \
    const int seg_ = (ch) >> 3, c_ = ((ch) & 7) * 128;                        \
    const char* As_ = (const char*)((seg_ == 0) ? A2 : A1);                   \
    const char* Bs_ = (const char*)((seg_ == 1) ? B2 : B1);                   \
    _Pragma("unroll") for (int i_ = 0; i_ < 2; ++i_)                          \
        gload16(As_ + aoff[i_] + c_, &lds[buf][dstA[i_]]);                    \
    _Pragma("unroll") for (int i_ = 0; i_ < 2; ++i_)                          \
        gload16(Bs_ + boff[i_] + c_, &lds[buf][dstB[i_]]);                    \
} while (0)

    f32x4 acc[2][2];
    #pragma unroll
    for (int i = 0; i < 2; ++i)
        #pragma unroll
        for (int j = 0; j < 2; ++j) acc[i][j] = (f32x4){0.f, 0.f, 0.f, 0.f};

    STAGE(0, 0);
    STAGE(1, 1);

    int bcur = 0, bst = 2;   // compute buffer / stage target (rotate mod 3)

    #pragma unroll 1
    for (int ch = 0; ch < NCH; ++ch) {
        // wait own chunk-ch loads (oldest 4), THEN barrier -> all waves' DMA in
        if (ch < NCH - 1) asm volatile("s_waitcnt vmcnt(4)" ::: "memory");
        else              asm volatile("s_waitcnt vmcnt(0)" ::: "memory");
        __builtin_amdgcn_s_barrier();
        asm volatile("" ::: "memory");
        // stage ch+2 into the free buffer; overlaps this chunk's compute.
        // (buf bst last read at iter ch-1; this iter's barrier protects it.)
        if (ch + 2 < NCH) STAGE(bst, ch + 2);

        const unsigned char* sAb = &lds[bcur][0];
        const unsigned char* sBb = &lds[bcur][8192];
        __builtin_amdgcn_s_setprio(1);
        #pragma unroll
        for (int ks = 0; ks < 2; ++ks) {
            const int kb = ks * 64 + lg * 16;
            half8 af[2], bf[2];
            #pragma unroll
            for (int i = 0; i < 2; ++i) {
                const int r_ = qr + i * 16 + li;
                af[i] = *(const half8*)(sAb + r_ * 128 + (kb ^ ((r_ & 7) << 4)));
            }
            #pragma unroll
            for (int j = 0; j < 2; ++j) {
                const int c_ = qc + j * 16 + li;
                bf[j] = *(const half8*)(sBb + c_ * 128 + (kb ^ ((c_ & 7) << 4)));
            }
            #pragma unroll
            for (int i = 0; i < 2; ++i)
                #pragma unroll
                for (int j = 0; j < 2; ++j)
                    acc[i][j] = __builtin_amdgcn_mfma_f32_16x16x32_f16(
                        af[i], bf[j], acc[i][j], 0, 0, 0);
        }
        __builtin_amdgcn_s_setprio(0);
        if (ch == 15) {   // end of scaled phase: undo the 2^11 residual scaling
            #pragma unroll
            for (int i = 0; i < 2; ++i)
                #pragma unroll
                for (int j = 0; j < 2; ++j)
                    acc[i][j] *= (1.0f / 2048.0f);
        }
        bcur = (bcur == 2) ? 0 : bcur + 1;
        bst  = (bst  == 2) ? 0 : bst  + 1;
    }

    float cb[2];
    #pragma unroll
    for (int j = 0; j < 2; ++j) cb[j] = bias[n0 + qc + j * 16 + li];

    // LIF recurrence: both layers identical -> simulate once.
    // spk_t == reset_{t+1}; fold reset: mem = fma(beta, mem, sp ? c-1 : c)
    #pragma unroll
    for (int i = 0; i < 2; ++i) {
        int rsum[4] = {0, 0, 0, 0};
        #pragma unroll
        for (int j = 0; j < 2; ++j) {
            float c[4], c1[4], mem[4];
            int cnt[4];
            bool sp[4];
            #pragma unroll
            for (int r = 0; r < 4; ++r) {
                c[r]   = acc[i][j][r] + cb[j];
                c1[r]  = c[r] - 1.0f;
                mem[r] = 0.0f;
                cnt[r] = 0;
                sp[r]  = false;
            }
            #pragma unroll 1
            for (int tt = 0; tt < TSTEPS; ++tt) {
                #pragma unroll
                for (int r = 0; r < 4; ++r) {
                    mem[r] = fmaf(0.95f, mem[r], sp[r] ? c1[r] : c[r]);
                    sp[r]  = mem[r] > 1.0f;
                    cnt[r] += sp[r] ? 1 : 0;
                }
            }
            const int col = n0 + qc + j * 16 + li;
            #pragma unroll
            for (int r = 0; r < 4; ++r) {
                const int row = m0 + qr + i * 16 + lg * 4 + r;
                agg[(size_t)row * NDIM + col] = (float)cnt[r];
                rsum[r] += cnt[r];
            }
        }
        // tot: integer counts, exact in fp32, order-independent atomics
        #pragma unroll
        for (int r = 0; r < 4; ++r) {
            int s = rsum[r];
            s += __shfl_xor(s, 1);
            s += __shfl_xor(s, 2);
            s += __shfl_xor(s, 4);
            s += __shfl_xor(s, 8);
            if (li == 0)
                atomicAdd(&tot[m0 + qr + i * 16 + lg * 4 + r], 2.0f * (float)s);
        }
        __builtin_amdgcn_sched_barrier(0);  // sequence i-blocks: cap liveness
    }
}

extern "C" void kernel_launch(void* const* d_in, const int* in_sizes, int n_in,
                              void* d_out, int out_size, void* d_ws, size_t ws_size,
                              hipStream_t stream) {
    const float* x = (const float*)d_in[0];
    const float* W = (const float*)d_in[1];
    const float* b = (const float*)d_in[2];
    float* agg = (float*)d_out;
    float* tot = agg + (size_t)MDIM * NDIM;

    char* ws = (char*)d_ws;                       // needs ws_size >= 10 MB
    _Float16* A1 = (_Float16*)(ws);               // 4 MB
    _Float16* A2 = (_Float16*)(ws + (4 << 20));   // 4 MB
    _Float16* B1 = (_Float16*)(ws + (8 << 20));   // 1 MB
    _Float16* B2 = (_Float16*)(ws + (9 << 20));   // 1 MB

    split_kernel<<<1024 + 256, 256, 0, stream>>>(x, W, A1, A2, B1, B2, tot);
    snn_mfma_kernel<<<(MDIM / 64) * (NDIM / 64), 256, 0, stream>>>(
        A1, A2, B1, B2, b, agg, tot);
}

// Round 12
// 54.444 us; speedup vs baseline: 1.1637x; 1.1637x over previous
//
#include <hip/hip_runtime.h>
#include <stdint.h>

#define MDIM 4096
#define NDIM 1024
#define KDIM 512
#define TSTEPS 50
#define NCH 16            // 16 chunks of BK=32; all 3 split-products per chunk

typedef _Float16 half8 __attribute__((ext_vector_type(8)));
typedef float    f32x4 __attribute__((ext_vector_type(4)));

typedef const __attribute__((address_space(1))) void cgv_t;
typedef __attribute__((address_space(3))) void lv_t;

__device__ __forceinline__ void gload16(const void* g, void* s) {
    __builtin_amdgcn_global_load_lds((cgv_t*)g, (lv_t*)s, 16, 0, 0);
}

// Pre-kernel: split fp32 -> (f16, f16 residual*2048) for A and W^T into
// k-major chunk images: band b (64 rows), chunk c (32 k), lane-group lg
// (8 k each): 16B slot s = row ^ (lg<<1)  at byte
//   band*65536 + c*4096 + lg*1024 + s*16.
// GEMM stages this linearly via global_load_lds (wave w copies the lg=w
// 1KB strip) and reads frags with the same XOR -> bank-uniform (8 words/bank
// per b128 = the 1KB-instruction floor).
__global__ __launch_bounds__(256) void split_kernel(
    const float* __restrict__ A, const float* __restrict__ W,
    char* __restrict__ A1, char* __restrict__ A2,
    char* __restrict__ B1, char* __restrict__ B2,
    float* __restrict__ tot)
{
    const int blk = blockIdx.x;
    if (blk < 1024) {               // A path: 262144 = 4096 rows x 16 c x 4 lg
        int idx = blk * 256 + threadIdx.x;
        if (idx < MDIM) tot[idx] = 0.0f;    // fused tot-zeroing
        int r = idx >> 6, q = idx & 63, c = q >> 2, lg = q & 3;
        const float* pA = A + (size_t)r * KDIM + c * 32 + lg * 8;
        float4 v0 = *(const float4*)pA;
        float4 v1 = *(const float4*)(pA + 4);
        float v[8] = {v0.x, v0.y, v0.z, v0.w, v1.x, v1.y, v1.z, v1.w};
        half8 h1, h2;
        #pragma unroll
        for (int e = 0; e < 8; ++e) {
            h1[e] = (_Float16)v[e];
            h2[e] = (_Float16)((v[e] - (float)h1[e]) * 2048.0f);
        }
        int off = (r >> 6) * 65536 + c * 4096 + lg * 1024
                + (((r & 63) ^ (lg << 1)) << 4);
        *(half8*)(A1 + off) = h1;
        *(half8*)(A2 + off) = h2;
    } else {                        // W path: 65536 = 64 (c,lg) x 1024 n
        int idx = (blk - 1024) * 256 + threadIdx.x;
        int q = idx >> 10, n = idx & 1023, c = q >> 2, lg = q & 3;
        float v[8];
        #pragma unroll
        for (int e = 0; e < 8; ++e)
            v[e] = W[(size_t)(c * 32 + lg * 8 + e) * NDIM + n];
        half8 h1, h2;
        #pragma unroll
        for (int e = 0; e < 8; ++e) {
            h1[e] = (_Float16)v[e];
            h2[e] = (_Float16)((v[e] - (float)h1[e]) * 2048.0f);
        }
        int off = (n >> 6) * 65536 + c * 4096 + lg * 1024
                + (((n & 63) ^ (lg << 1)) << 4);
        *(half8*)(B1 + off) = h1;
        *(half8*)(B2 + off) = h2;
    }
}

// Fused split-2 f16 MFMA GEMM + LIF. Per chunk (BK=32): stage A1|A2|B1|B2
// (16KB), read 8 b128 frags, 12 MFMA:
//   acc_hi += a2s*b1 ; acc_hi += a1*b2s ; acc_lo += a1*b1
// out = acc_lo + acc_hi * 2^-11.  64x64 tile, 256 thr (4 waves, wave = 32x32
// = 2x2 frags of 16x16x32), 4 blocks/CU. R10-proven sync: 2 barriers/chunk,
// counted vmcnt(4), stage-after-compute, 2 LDS buffers (32KB).
__global__ __launch_bounds__(256, 4) void snn_mfma_kernel(
    const char* __restrict__ A1, const char* __restrict__ A2,
    const char* __restrict__ B1, const char* __restrict__ B2,
    const float* __restrict__ bias, float* __restrict__ agg, float* __restrict__ tot)
{
    __shared__ __align__(16) unsigned char lds[2][16384]; // A1|A2|B1|B2 4KB each

    const int t  = threadIdx.x;
    const int l  = t & 63;
    const int w  = t >> 6;
    const int li = l & 15;
    const int lg = l >> 4;
    const int qr = (w >> 1) * 32;   // wave quadrant
    const int qc = (w & 1) * 32;

    // XCD swizzle (bijective, 1024 = 8 x 128)
    const int swz = (blockIdx.x & 7) * 128 + (blockIdx.x >> 3);
    const int m0 = (swz >> 4) * 64;
    const int n0 = (swz & 15) * 64;

    // staging: 4 gload16/thread/chunk (one per image); wave w copies lg=w strip
    const int aoff = (m0 >> 6) * 65536 + w * 1024 + l * 16;
    const int boff = (n0 >> 6) * 65536 + w * 1024 + l * 16;
    const int dstw = w * 1024;

#define STAGE(buf, ch) do {                                                   \
    const int c_ = (ch) * 4096;                                               \
    gload16(A1 + aoff + c_, &lds[buf][dstw]);                                 \
    gload16(A2 + aoff + c_, &lds[buf][4096  + dstw]);                         \
    gload16(B1 + boff + c_, &lds[buf][8192  + dstw]);                         \
    gload16(B2 + boff + c_, &lds[buf][12288 + dstw]);                         \
} while (0)

    // loop-invariant frag byte offsets (XOR matches the baked image layout)
    int aL[2], bL[2];
    #pragma unroll
    for (int i = 0; i < 2; ++i) {
        aL[i] = lg * 1024 + (((qr + i * 16 + li) ^ (lg << 1)) << 4);
        bL[i] = lg * 1024 + (((qc + i * 16 + li) ^ (lg << 1)) << 4);
    }

    f32x4 acc_lo[2][2], acc_hi[2][2];
    #pragma unroll
    for (int i = 0; i < 2; ++i)
        #pragma unroll
        for (int j = 0; j < 2; ++j) {
            acc_lo[i][j] = (f32x4){0.f, 0.f, 0.f, 0.f};
            acc_hi[i][j] = (f32x4){0.f, 0.f, 0.f, 0.f};
        }

    STAGE(0, 0);
    STAGE(1, 1);

    #pragma unroll 1
    for (int ch = 0; ch < NCH; ++ch) {
        if (ch < NCH - 1) asm volatile("s_waitcnt vmcnt(4)" ::: "memory");
        else              asm volatile("s_waitcnt vmcnt(0)" ::: "memory");
        __builtin_amdgcn_s_barrier();
        asm volatile("" ::: "memory");
        const unsigned char* sb = lds[ch & 1];

        half8 af1[2], af2[2], bf1[2], bf2[2];
        #pragma unroll
        for (int i = 0; i < 2; ++i) {
            af1[i] = *(const half8*)(sb + aL[i]);
            af2[i] = *(const half8*)(sb + 4096 + aL[i]);
            bf1[i] = *(const half8*)(sb + 8192 + bL[i]);
            bf2[i] = *(const half8*)(sb + 12288 + bL[i]);
        }
        #pragma unroll
        for (int i = 0; i < 2; ++i)
            #pragma unroll
            for (int j = 0; j < 2; ++j)
                acc_hi[i][j] = __builtin_amdgcn_mfma_f32_16x16x32_f16(
                    af2[i], bf1[j], acc_hi[i][j], 0, 0, 0);
        #pragma unroll
        for (int i = 0; i < 2; ++i)
            #pragma unroll
            for (int j = 0; j < 2; ++j)
                acc_hi[i][j] = __builtin_amdgcn_mfma_f32_16x16x32_f16(
                    af1[i], bf2[j], acc_hi[i][j], 0, 0, 0);
        #pragma unroll
        for (int i = 0; i < 2; ++i)
            #pragma unroll
            for (int j = 0; j < 2; ++j)
                acc_lo[i][j] = __builtin_amdgcn_mfma_f32_16x16x32_f16(
                    af1[i], bf1[j], acc_lo[i][j], 0, 0, 0);

        __builtin_amdgcn_s_barrier();
        asm volatile("" ::: "memory");
        if (ch + 2 < NCH) STAGE(ch & 1, ch + 2);
    }

    float cb[2];
    #pragma unroll
    for (int j = 0; j < 2; ++j) cb[j] = bias[n0 + qc + j * 16 + li];

    // LIF recurrence: both layers identical -> simulate once.
    // spk_t == reset_{t+1}; fold reset: mem = fma(beta, mem, sp ? c-1 : c)
    #pragma unroll
    for (int i = 0; i < 2; ++i) {
        int rsum[4] = {0, 0, 0, 0};
        #pragma unroll
        for (int j = 0; j < 2; ++j) {
            float c[4], c1[4], mem[4];
            int cnt[4];
            bool sp[4];
            #pragma unroll
            for (int r = 0; r < 4; ++r) {
                c[r]   = fmaf(acc_hi[i][j][r], 4.8828125e-4f, acc_lo[i][j][r])
                       + cb[j];
                c1[r]  = c[r] - 1.0f;
                mem[r] = 0.0f;
                cnt[r] = 0;
                sp[r]  = false;
            }
            #pragma unroll 1
            for (int tt = 0; tt < TSTEPS; ++tt) {
                #pragma unroll
                for (int r = 0; r < 4; ++r) {
                    mem[r] = fmaf(0.95f, mem[r], sp[r] ? c1[r] : c[r]);
                    sp[r]  = mem[r] > 1.0f;
                    cnt[r] += sp[r] ? 1 : 0;
                }
            }
            const int col = n0 + qc + j * 16 + li;
            #pragma unroll
            for (int r = 0; r < 4; ++r) {
                const int row = m0 + qr + i * 16 + lg * 4 + r;
                agg[(size_t)row * NDIM + col] = (float)cnt[r];
                rsum[r] += cnt[r];
            }
        }
        // tot: integer counts, exact in fp32, order-independent atomics
        #pragma unroll
        for (int r = 0; r < 4; ++r) {
            int s = rsum[r];
            s += __shfl_xor(s, 1);
            s += __shfl_xor(s, 2);
            s += __shfl_xor(s, 4);
            s += __shfl_xor(s, 8);
            if (li == 0)
                atomicAdd(&tot[m0 + qr + i * 16 + lg * 4 + r], 2.0f * (float)s);
        }
        __builtin_amdgcn_sched_barrier(0);  // sequence i-blocks: cap liveness
    }
}

extern "C" void kernel_launch(void* const* d_in, const int* in_sizes, int n_in,
                              void* d_out, int out_size, void* d_ws, size_t ws_size,
                              hipStream_t stream) {
    const float* x = (const float*)d_in[0];
    const float* W = (const float*)d_in[1];
    const float* b = (const float*)d_in[2];
    float* agg = (float*)d_out;
    float* tot = agg + (size_t)MDIM * NDIM;

    char* ws = (char*)d_ws;           // needs ws_size >= 10 MB
    char* A1 = ws;                    // 4 MB
    char* A2 = ws + (4 << 20);        // 4 MB
    char* B1 = ws + (8 << 20);        // 1 MB
    char* B2 = ws + (9 << 20);        // 1 MB

    split_kernel<<<1024 + 256, 256, 0, stream>>>(x, W, A1, A2, B1, B2,
                                                 (float*)tot);
    snn_mfma_kernel<<<(MDIM / 64) * (NDIM / 64), 256, 0, stream>>>(
        A1, A2, B1, B2, b, agg, tot);
}